// Round 1
// baseline (146.167 us; speedup 1.0000x reference)
//
#include <hip/hip_runtime.h>
#include <hip/hip_bf16.h>

typedef __attribute__((ext_vector_type(4))) float f32x4;
typedef __attribute__((ext_vector_type(8))) short bf16x8;

static __device__ __forceinline__ unsigned short f2bf(float f) {
    unsigned int u = __float_as_uint(f);
    unsigned int r = (u + 0x7FFFu + ((u >> 16) & 1u)) >> 16;   // RNE
    return (unsigned short)r;
}

// ---- prep 1: W[p][f][c] = bf16(exp(k1)-exp(k2)), transposed so c is contiguous ----
__global__ __launch_bounds__(256) void wprep_kernel(const float* __restrict__ k1,
                                                    const float* __restrict__ k2,
                                                    unsigned short* __restrict__ wp) {
    int idx = blockIdx.x * 256 + threadIdx.x;          // [p][f][c], 9*128*64
    if (idx >= 9 * 128 * 64) return;
    int c = idx & 63;
    int f = (idx >> 6) & 127;
    int p = idx >> 13;
    int src = (p * 64 + c) * 128 + f;                  // k1/k2 are (p, c, f)
    float v = expf(k1[src]) - expf(k2[src]);
    wp[idx] = f2bf(v);
}

// ---- prep 2: x NCHW f32 -> NHWC bf16 (per-image (C,HW) transpose via LDS) ----
__global__ __launch_bounds__(256) void xprep_kernel(const float* __restrict__ x,
                                                    unsigned short* __restrict__ xo) {
    __shared__ float t[64][65];
    int b   = blockIdx.x >> 6;          // 32 images
    int hwt = blockIdx.x & 63;          // 64 tiles of 64 pixels
    int hw0 = hwt * 64;
    int lane = threadIdx.x & 63;
    int part = threadIdx.x >> 6;        // 0..3
    const float* xb = x + b * (64 * 4096);
#pragma unroll
    for (int i = 0; i < 16; ++i) {
        int c = i * 4 + part;
        t[c][lane] = xb[c * 4096 + hw0 + lane];        // coalesced over hw
    }
    __syncthreads();
    unsigned short* xob = xo + b * (4096 * 64);
#pragma unroll
    for (int i = 0; i < 16; ++i) {
        int hw = i * 4 + part;
        xob[(hw0 + hw) * 64 + lane] = f2bf(t[lane][hw]);  // coalesced over c
    }
}

// ---- main: implicit-GEMM conv, M=128 (2 rows x 64 ow-pad), N=128 (F), K=576 ----
__global__ __launch_bounds__(256, 3) void conv_kernel(const unsigned short* __restrict__ xn,
                                                      const unsigned short* __restrict__ wp,
                                                      const float* __restrict__ bias,
                                                      float* __restrict__ out) {
    __shared__ unsigned short xs[4 * 66 * 64];   // 33792 B, swizzled, staged once
    __shared__ unsigned short bs[128 * 64];      // 16384 B, per-position weights

    int bid0 = blockIdx.x;                       // 992 = 8 * 124
    int bid  = (bid0 & 7) * 124 + (bid0 >> 3);   // XCD-chunked swizzle (bijective)
    int b    = bid / 31;
    int tile = bid - b * 31;
    int oh0  = tile * 2;                         // rows oh0, oh0+1 ; x rows oh0..oh0+3 (<=63)

    int tid = threadIdx.x;
    const unsigned short* xb = xn + b * (4096 * 64);
    const uint4* wp16 = (const uint4*)wp;

    // prefetch pos-0 weights into regs (16 KB / 256 thr = 4 x 16 B)
    uint4 wreg[4];
#pragma unroll
    for (int i2 = 0; i2 < 4; ++i2) wreg[i2] = wp16[i2 * 256 + tid];

    // stage x tile: rows 0..3, cols 0..65 (clamped), all 64 c ; swizzle c ^= (col&7)<<3
    for (int q = tid; q < 4 * 66 * 8; q += 256) {
        int cc  = q & 7;
        int pix = q >> 3;
        int col = pix % 66;
        int row = pix / 66;
        int colg = col > 63 ? 63 : col;          // clamp: only feeds masked-out outputs
        uint4 v = *(const uint4*)(xb + ((oh0 + row) * 64 + colg) * 64 + cc * 8);
        *(uint4*)(&xs[(row * 66 + col) * 64 + ((cc * 8) ^ ((col & 7) << 3))]) = v;
    }

    int lane = tid & 63;
    int wid  = tid >> 6;
    int wr = wid >> 1;           // output row within tile (0..1)
    int wc = wid & 1;            // f-half (0..1)
    int lr  = lane & 15;
    int lk8 = (lane >> 4) << 3;

    f32x4 acc[4][4];
#pragma unroll
    for (int mi = 0; mi < 4; ++mi)
#pragma unroll
        for (int ni = 0; ni < 4; ++ni) acc[mi][ni] = (f32x4){0.f, 0.f, 0.f, 0.f};

#pragma unroll
    for (int p = 0; p < 9; ++p) {
        __syncthreads();                          // prior reads of bs done / xs visible
#pragma unroll
        for (int i2 = 0; i2 < 4; ++i2) {          // commit weights pos p (swizzled)
            int q = i2 * 256 + tid;
            int f = q >> 3, cc = q & 7;
            *(uint4*)(&bs[f * 64 + ((cc * 8) ^ ((f & 7) << 3))]) = wreg[i2];
        }
        if (p < 8) {                              // T14: issue next-pos loads early
#pragma unroll
            for (int i2 = 0; i2 < 4; ++i2) wreg[i2] = wp16[(p + 1) * 1024 + i2 * 256 + tid];
        }
        __syncthreads();
        const int ki = p / 3, kj = p % 3;         // const under full unroll
#pragma unroll
        for (int kb = 0; kb < 64; kb += 32) {
            int c0 = kb + lk8;
            bf16x8 af[4], bfr[4];
#pragma unroll
            for (int mi = 0; mi < 4; ++mi) {
                int col = mi * 16 + lr + kj;      // ow + kj
                af[mi] = *(const bf16x8*)(&xs[((wr + ki) * 66 + col) * 64 + (c0 ^ ((col & 7) << 3))]);
            }
#pragma unroll
            for (int ni = 0; ni < 4; ++ni) {
                int f = wc * 64 + ni * 16 + lr;
                bfr[ni] = *(const bf16x8*)(&bs[f * 64 + (c0 ^ ((f & 7) << 3))]);
            }
#pragma unroll
            for (int mi = 0; mi < 4; ++mi)
#pragma unroll
                for (int ni = 0; ni < 4; ++ni)
                    acc[mi][ni] = __builtin_amdgcn_mfma_f32_16x16x32_bf16(af[mi], bfr[ni], acc[mi][ni], 0, 0, 0);
        }
    }

    // epilogue: D row = (lane>>4)*4 + t (ow), col = lane&15 (f)  [m89 layout]
    int oh = oh0 + wr;
    float* ob = out + b * (128 * 62 * 62);
#pragma unroll
    for (int ni = 0; ni < 4; ++ni) {
        int f = wc * 64 + ni * 16 + lr;
        float bv = bias[f];
        float* orow = ob + (f * 62 + oh) * 62;
#pragma unroll
        for (int mi = 0; mi < 4; ++mi) {
#pragma unroll
            for (int t = 0; t < 4; ++t) {
                int ow = mi * 16 + ((lane >> 4) << 2) + t;
                if (ow < 62) orow[ow] = acc[mi][ni][t] + bv;
            }
        }
    }
}

extern "C" void kernel_launch(void* const* d_in, const int* in_sizes, int n_in,
                              void* d_out, int out_size, void* d_ws, size_t ws_size,
                              hipStream_t stream) {
    const float* x    = (const float*)d_in[0];
    const float* k1   = (const float*)d_in[1];
    const float* k2   = (const float*)d_in[2];
    const float* bias = (const float*)d_in[3];
    float* out = (float*)d_out;

    unsigned short* wp = (unsigned short*)d_ws;              // 9*128*64  = 147456 B
    unsigned short* xn = (unsigned short*)d_ws + 73728;      // 32*4096*64*2 = 16.78 MB

    hipLaunchKernelGGL(wprep_kernel, dim3(288), dim3(256), 0, stream, k1, k2, wp);
    hipLaunchKernelGGL(xprep_kernel, dim3(2048), dim3(256), 0, stream, x, xn);
    hipLaunchKernelGGL(conv_kernel, dim3(992), dim3(256), 0, stream, xn, wp, bias, out);
}

// Round 2
// 138.223 us; speedup vs baseline: 1.0575x; 1.0575x over previous
//
#include <hip/hip_runtime.h>
#include <hip/hip_bf16.h>

typedef __attribute__((ext_vector_type(4))) float f32x4;
typedef __attribute__((ext_vector_type(8))) short bf16x8;

static __device__ __forceinline__ unsigned short f2bf(float f) {
    unsigned int u = __float_as_uint(f);
    unsigned int r = (u + 0x7FFFu + ((u >> 16) & 1u)) >> 16;   // RNE
    return (unsigned short)r;
}

// ---- prep: W[p][f][c] = bf16(exp(k1)-exp(k2)), transposed so c is contiguous ----
__global__ __launch_bounds__(256) void wprep_kernel(const float* __restrict__ k1,
                                                    const float* __restrict__ k2,
                                                    unsigned short* __restrict__ wp) {
    int idx = blockIdx.x * 256 + threadIdx.x;          // [p][f][c], 9*128*64
    if (idx >= 9 * 128 * 64) return;
    int c = idx & 63;
    int f = (idx >> 6) & 127;
    int p = idx >> 13;
    int src = (p * 64 + c) * 128 + f;                  // k1/k2 are (p, c, f)
    float v = expf(k1[src]) - expf(k2[src]);
    wp[idx] = f2bf(v);
}

// ---- main: fused NCHW->tile transpose + implicit-GEMM conv ----
// M = 128 F, N = 128 (2 oh rows x 64 ow-pad), K = 576. Per block: 1 image, 2 output rows.
__global__ __launch_bounds__(256, 3) void conv_kernel(const float* __restrict__ x,
                                                      const unsigned short* __restrict__ wp,
                                                      const float* __restrict__ bias,
                                                      float* __restrict__ out) {
    __shared__ unsigned short xs[4 * 64 * 64];   // 32768 B: [row][col][c], c swizzled
    __shared__ unsigned short bs[128 * 64];      // 16384 B: per-position weights [f][c]

    int bid0 = blockIdx.x;                       // 992 = 8 * 124
    int bid  = (bid0 & 7) * 124 + (bid0 >> 3);   // XCD-chunked swizzle (bijective)
    int b    = bid / 31;
    int tile = bid - b * 31;
    int oh0  = tile * 2;                         // output rows oh0, oh0+1; x rows oh0..oh0+3

    int tid  = threadIdx.x;
    int lane = tid & 63;
    const float* xb = x + b * (64 * 4096);
    const uint4* wp16 = (const uint4*)wp;

    // prefetch pos-0 weights into regs (16 KB / 256 thr = 4 x 16 B)
    uint4 wreg[4];
#pragma unroll
    for (int i2 = 0; i2 < 4; ++i2) wreg[i2] = wp16[i2 * 256 + tid];

    // fused stage: NCHW f32 -> bf16 [row][col][c^swz]; wave = 64 consecutive cols
    {
        int col = tid & 63;
        int u0  = tid >> 6;                      // wave id
#pragma unroll
        for (int j = 0; j < 8; ++j) {
            int u   = u0 + j * 4;                // 0..31
            int row = u >> 3;                    // 0..3
            int cg  = u & 7;                     // channel group of 8
            float v[8];
#pragma unroll
            for (int e = 0; e < 8; ++e)
                v[e] = xb[(cg * 8 + e) * 4096 + (oh0 + row) * 64 + col];  // coalesced over col
            uint4 pk;
            pk.x = (unsigned int)f2bf(v[0]) | ((unsigned int)f2bf(v[1]) << 16);
            pk.y = (unsigned int)f2bf(v[2]) | ((unsigned int)f2bf(v[3]) << 16);
            pk.z = (unsigned int)f2bf(v[4]) | ((unsigned int)f2bf(v[5]) << 16);
            pk.w = (unsigned int)f2bf(v[6]) | ((unsigned int)f2bf(v[7]) << 16);
            *(uint4*)(&xs[((row * 64 + col) << 6) + ((cg * 8) ^ ((col & 7) << 3))]) = pk;
        }
    }

    int wid = tid >> 6;
    int wr  = wid >> 1;          // output row within tile (0..1)
    int wc  = wid & 1;           // f-half (0..1)
    int lr  = lane & 15;
    int lk8 = (lane >> 4) << 3;

    f32x4 acc[4][4];             // [ni: f-block][mi: ow-block]
#pragma unroll
    for (int ni = 0; ni < 4; ++ni)
#pragma unroll
        for (int mi = 0; mi < 4; ++mi) acc[ni][mi] = (f32x4){0.f, 0.f, 0.f, 0.f};

#pragma unroll
    for (int p = 0; p < 9; ++p) {
        __syncthreads();                          // prior bs reads done / xs visible (p==0)
#pragma unroll
        for (int i2 = 0; i2 < 4; ++i2) {          // commit weights pos p (swizzled)
            int q = i2 * 256 + tid;
            int f = q >> 3, cc = q & 7;
            *(uint4*)(&bs[f * 64 + ((cc * 8) ^ ((f & 7) << 3))]) = wreg[i2];
        }
        if (p < 8) {                              // issue next-pos loads early
#pragma unroll
            for (int i2 = 0; i2 < 4; ++i2) wreg[i2] = wp16[(p + 1) * 1024 + i2 * 256 + tid];
        }
        __syncthreads();
        const int ki = p / 3, kj = p % 3;
#pragma unroll
        for (int kb = 0; kb < 64; kb += 32) {
            int c0 = kb + lk8;
            bf16x8 af[4], bfr[4];
#pragma unroll
            for (int mi = 0; mi < 4; ++mi) {
                int col  = mi * 16 + lr + kj;     // ow + kj, <= 65
                int colc = col > 63 ? 63 : col;   // clamped cols only feed masked ow>=62
                af[mi] = *(const bf16x8*)(&xs[(((wr + ki) * 64 + colc) << 6) + (c0 ^ ((colc & 7) << 3))]);
            }
#pragma unroll
            for (int ni = 0; ni < 4; ++ni) {
                int f = wc * 64 + ni * 16 + lr;
                bfr[ni] = *(const bf16x8*)(&bs[f * 64 + (c0 ^ ((f & 7) << 3))]);
            }
#pragma unroll
            for (int ni = 0; ni < 4; ++ni)
#pragma unroll
                for (int mi = 0; mi < 4; ++mi)     // A = weights (m=f), B = x (n=ow)
                    acc[ni][mi] = __builtin_amdgcn_mfma_f32_16x16x32_bf16(bfr[ni], af[mi], acc[ni][mi], 0, 0, 0);
        }
    }

    // epilogue: D row = f = (lane>>4)*4+t, col = ow = lane&15 -> coalesced over ow
    int oh = oh0 + wr;
    float* ob = out + b * (128 * 62 * 62);
#pragma unroll
    for (int ni = 0; ni < 4; ++ni) {
        int fb = wc * 64 + ni * 16 + ((lane >> 4) << 2);
        f32x4 bv4 = *(const f32x4*)(bias + fb);     // 4 f-values for t=0..3
#pragma unroll
        for (int t = 0; t < 4; ++t) {
            int f = fb + t;
            float* orow = ob + (f * 62 + oh) * 62;
#pragma unroll
            for (int mi = 0; mi < 4; ++mi) {
                int ow = mi * 16 + lr;
                if (ow < 62) orow[ow] = acc[ni][mi][t] + bv4[t];
            }
        }
    }
}

extern "C" void kernel_launch(void* const* d_in, const int* in_sizes, int n_in,
                              void* d_out, int out_size, void* d_ws, size_t ws_size,
                              hipStream_t stream) {
    const float* x    = (const float*)d_in[0];
    const float* k1   = (const float*)d_in[1];
    const float* k2   = (const float*)d_in[2];
    const float* bias = (const float*)d_in[3];
    float* out = (float*)d_out;

    unsigned short* wp = (unsigned short*)d_ws;              // 9*128*64 bf16 = 147456 B

    hipLaunchKernelGGL(wprep_kernel, dim3(288), dim3(256), 0, stream, k1, k2, wp);
    hipLaunchKernelGGL(conv_kernel, dim3(992), dim3(256), 0, stream, x, wp, bias, out);
}

// Round 3
// 133.001 us; speedup vs baseline: 1.0990x; 1.0393x over previous
//
#include <hip/hip_runtime.h>
#include <hip/hip_bf16.h>

typedef __attribute__((ext_vector_type(4))) float f32x4;
typedef __attribute__((ext_vector_type(8))) short bf16x8;

static __device__ __forceinline__ unsigned int f2bf(float f) {
    unsigned int u = __float_as_uint(f);
    return (u + 0x7FFFu + ((u >> 16) & 1u)) >> 16;   // RNE
}

// ---- prep: W fragment-ordered wq[p][kh][f][ch] = bf16(exp(k1)-exp(k2)) ----
// (p = 3x3 position, kh = c-half (32), f = 0..127, ch = c within half)
// Each wave A-fragment read (fixed p,kh,ni,wc) is then 1 KB dense & coalesced.
__global__ __launch_bounds__(256) void wprep_kernel(const float* __restrict__ k1,
                                                    const float* __restrict__ k2,
                                                    unsigned short* __restrict__ wq) {
    int idx = blockIdx.x * 256 + threadIdx.x;          // 9*2*128*32 = 73728
    if (idx >= 73728) return;
    int f  = idx & 127;
    int ch = (idx >> 7) & 31;
    int kh = (idx >> 12) & 1;
    int p  = idx >> 13;
    int src = (p * 64 + kh * 32 + ch) * 128 + f;       // k1/k2 are (p, c, f); f contiguous
    float v = expf(k1[src]) - expf(k2[src]);
    wq[((p * 2 + kh) * 128 + f) * 32 + ch] = (unsigned short)f2bf(v);
}

// ---- main: fused NCHW->tile transpose + implicit-GEMM conv, ONE barrier total ----
// M = 128 F, N = 128 (2 oh rows x 64 ow-pad), K = 576. Per block: 1 image, 2 output rows.
// Weights: global->register double-buffer (no LDS, no per-p barriers).
__global__ __launch_bounds__(256, 3) void conv_kernel(const float* __restrict__ x,
                                                      const unsigned short* __restrict__ wq,
                                                      const float* __restrict__ bias,
                                                      float* __restrict__ out) {
    __shared__ unsigned short xs[4 * 64 * 64];   // 32768 B: [row][col][c], c swizzled

    int bid0 = blockIdx.x;                       // 992 = 8 * 124
    int bid  = (bid0 & 7) * 124 + (bid0 >> 3);   // XCD-chunked swizzle (bijective)
    int b    = bid / 31;
    int tile = bid - b * 31;
    int oh0  = tile * 2;                         // output rows oh0, oh0+1; x rows oh0..oh0+3

    int tid  = threadIdx.x;
    int lane = tid & 63;
    int wid  = tid >> 6;
    int wr   = wid >> 1;         // output row within tile (0..1)
    int wc   = wid & 1;          // f-half (0..1)
    int lr   = lane & 15;
    int hi   = lane >> 4;        // 0..3

    const float* xb = x + b * (64 * 4096);

    // ---- stage x: NCHW f32 -> bf16 [row][col][c^swz]; wave = 64 consecutive cols ----
    {
        int col = tid & 63;
#pragma unroll
        for (int j = 0; j < 8; ++j) {
            int u   = wid + j * 4;               // 0..31
            int row = u >> 3;                    // 0..3
            int cg  = u & 7;                     // channel group of 8
            float v[8];
#pragma unroll
            for (int e = 0; e < 8; ++e)
                v[e] = xb[(cg * 8 + e) * 4096 + (oh0 + row) * 64 + col];  // coalesced over col
            uint4 pk;
            pk.x = f2bf(v[0]) | (f2bf(v[1]) << 16);
            pk.y = f2bf(v[2]) | (f2bf(v[3]) << 16);
            pk.z = f2bf(v[4]) | (f2bf(v[5]) << 16);
            pk.w = f2bf(v[6]) | (f2bf(v[7]) << 16);
            *(uint4*)(&xs[((row * 64 + col) << 6) + ((cg * 8) ^ ((col & 7) << 3))]) = pk;
        }
    }

    // ---- prologue: W fragments for p=0 into registers ----
    const bf16x8* wg = (const bf16x8*)wq;        // 16-B fragment units
    int fb0 = wc * 64 + lr;                      // + ni*16 -> f row of this lane
    bf16x8 wfrag[2][8];                          // [buf][kh*4+ni], all indices static
#pragma unroll
    for (int kh = 0; kh < 2; ++kh)
#pragma unroll
        for (int ni = 0; ni < 4; ++ni)
            wfrag[0][kh * 4 + ni] = wg[((kh) * 128 + fb0 + ni * 16) * 4 + hi];

    f32x4 acc[4][4];                             // [ni: f-block][mi: ow-block]
#pragma unroll
    for (int ni = 0; ni < 4; ++ni)
#pragma unroll
        for (int mi = 0; mi < 4; ++mi) acc[ni][mi] = (f32x4){0.f, 0.f, 0.f, 0.f};

    __syncthreads();                             // the ONLY barrier

#pragma unroll
    for (int p = 0; p < 9; ++p) {
        const int cur = p & 1, nxt = cur ^ 1;
        if (p < 8) {                             // issue next-p weight loads early
#pragma unroll
            for (int kh = 0; kh < 2; ++kh)
#pragma unroll
                for (int ni = 0; ni < 4; ++ni)
                    wfrag[nxt][kh * 4 + ni] = wg[(((p + 1) * 2 + kh) * 128 + fb0 + ni * 16) * 4 + hi];
        }
        const int ki = p / 3, kj = p % 3;
#pragma unroll
        for (int kb = 0; kb < 2; ++kb) {
            int c0 = kb * 32 + hi * 8;
            bf16x8 af[4];
#pragma unroll
            for (int mi = 0; mi < 4; ++mi) {
                int col  = mi * 16 + lr + kj;    // ow + kj, <= 65
                int colc = col > 63 ? 63 : col;  // clamped cols only feed masked ow>=62
                af[mi] = *(const bf16x8*)(&xs[(((wr + ki) * 64 + colc) << 6) + (c0 ^ ((colc & 7) << 3))]);
            }
#pragma unroll
            for (int ni = 0; ni < 4; ++ni)
#pragma unroll
                for (int mi = 0; mi < 4; ++mi)   // A = weights (m=f), B = x (n=ow)
                    acc[ni][mi] = __builtin_amdgcn_mfma_f32_16x16x32_bf16(
                        wfrag[cur][kb * 4 + ni], af[mi], acc[ni][mi], 0, 0, 0);
        }
    }

    // ---- epilogue: D row = f = hi*4+t, col = ow = lr -> coalesced over ow ----
    int oh = oh0 + wr;
    float* ob = out + b * (128 * 62 * 62);
#pragma unroll
    for (int ni = 0; ni < 4; ++ni) {
        int fb = wc * 64 + ni * 16 + (hi << 2);
        f32x4 bv4 = *(const f32x4*)(bias + fb);
#pragma unroll
        for (int t = 0; t < 4; ++t) {
            float* orow = ob + ((fb + t) * 62 + oh) * 62;
#pragma unroll
            for (int mi = 0; mi < 4; ++mi) {
                int ow = mi * 16 + lr;
                if (ow < 62) orow[ow] = acc[ni][mi][t] + bv4[t];
            }
        }
    }
}

extern "C" void kernel_launch(void* const* d_in, const int* in_sizes, int n_in,
                              void* d_out, int out_size, void* d_ws, size_t ws_size,
                              hipStream_t stream) {
    const float* x    = (const float*)d_in[0];
    const float* k1   = (const float*)d_in[1];
    const float* k2   = (const float*)d_in[2];
    const float* bias = (const float*)d_in[3];
    float* out = (float*)d_out;

    unsigned short* wq = (unsigned short*)d_ws;              // 73728 bf16 = 147456 B

    hipLaunchKernelGGL(wprep_kernel, dim3(288), dim3(256), 0, stream, k1, k2, wq);
    hipLaunchKernelGGL(conv_kernel, dim3(992), dim3(256), 0, stream, x, wq, bias, out);
}